// Round 1
// baseline (146.326 us; speedup 1.0000x reference)
//
#include <hip/hip_runtime.h>

// GruDirection3d forward, d1=d2=d3=1. B=2, C=96, D=H=W=32.
// out[b,c,d,y,x] = z*h_tilde + (1-z)*out[b,c,d-1,y-1,x-1], border = h0.
//
// Key fact: the dependency is ONLY along the (1,1,1) diagonal, so the volume
// splits into 32^3 - 31^3 = 2977 independent 1D recurrences ("chains") per
// (b,c) slab, one per voxel on the d=0 / y=0 / x=0 entry faces. Chain from
// (d0,y0,x0) visits (d0+k, y0+k, x0+k) for k < 32 - max(d0,y0,x0).
//
// One thread per chain: no barriers, no LDS, ~571k threads -> machine-filling
// TLP. Chains entering on the d=0 / y=0 faces have lanes consecutive in x ->
// fully coalesced walks. x=0-face chains (32% of voxels) walk at 128B lane
// stride; they are packed so each face lives almost entirely in one
// 1024-thread block, so the cache line touched at step k is re-consumed at
// steps k+1.. by lanes 32,64,.. earlier in the same block (L1/L2 reuse).

#define SLAB   32768            // 32*32*32
#define STRIDE 1057             // (1,1,1) step = 32*32 + 32 + 1

__global__ __launch_bounds__(1024) void gru3d_diag(
    const float* __restrict__ z,
    const float* __restrict__ ht,
    const float* __restrict__ h0p,
    float* __restrict__ out)
{
    const int tid  = threadIdx.x;
    const int slab = blockIdx.x / 3;          // 0..191  (b*96 + c)
    const int i    = (blockIdx.x % 3) * 1024 + tid;   // chain id in slab, 0..3071

    // Decode chain start (d0,y0,x0) on one of the three entry faces.
    int d0, y0, x0;
    if (i < 1024) {                 // d = 0 face: all (y0, x0)
        d0 = 0;
        y0 = i >> 5;
        x0 = i & 31;
    } else if (i < 2016) {          // y = 0 face: d0 >= 1, all x0
        const int j = i - 1024;
        d0 = 1 + (j >> 5);
        y0 = 0;
        x0 = j & 31;
    } else if (i < 2977) {          // x = 0 face: d0 >= 1, y0 >= 1
        const int j = i - 2016;
        d0 = 1 + j / 31;            // compiler magic-mul, no HW divide
        y0 = 1 + j % 31;
        x0 = 0;
    } else {
        return;                      // 95 idle threads per slab
    }

    const int len = 32 - max(d0, max(y0, x0));   // chain length, 1..32

    const float h0 = h0p[0];
    const size_t base = (size_t)slab * SLAB + (size_t)(d0 * 1024 + y0 * 32 + x0);
    const float* __restrict__ zp = z   + base;
    const float* __restrict__ tp = ht  + base;
    float*       __restrict__ op = out + base;

    // Serial recurrence along the diagonal. Loads are address-independent of
    // the h chain, so unroll-by-4 batches 8 outstanding loads per thread.
    float h = h0;
    #pragma unroll 4
    for (int k = 0; k < len; ++k) {
        const float zv = zp[(size_t)k * STRIDE];
        const float tv = tp[(size_t)k * STRIDE];
        h += zv * (tv - h);          // == z*ht + (1-z)*h, one sub + one fma
        op[(size_t)k * STRIDE] = h;
    }
}

extern "C" void kernel_launch(void* const* d_in, const int* in_sizes, int n_in,
                              void* d_out, int out_size, void* d_ws, size_t ws_size,
                              hipStream_t stream) {
    const float* z  = (const float*)d_in[0];
    const float* ht = (const float*)d_in[1];
    const float* h0 = (const float*)d_in[2];
    float* out      = (float*)d_out;

    const int BC = 2 * 96;                    // 192 slabs
    gru3d_diag<<<dim3(BC * 3), dim3(1024), 0, stream>>>(z, ht, h0, out);
}

// Round 2
// 95.030 us; speedup vs baseline: 1.5398x; 1.5398x over previous
//
#include <hip/hip_runtime.h>

// GruDirection3d forward, d1=d2=d3=1. B=2, C=96, D=H=W=32.
// out[b,c,d,y,x] = z*h_tilde + (1-z)*out[b,c,d-1,y-1,x-1], border = h0.
//
// Plane-wavefront DP with FULL register preload: one 1024-thread block per
// (b,c) slab; thread (y,x) owns one element of every d-plane. All 32 planes
// of z and h_tilde (64 floats/thread) are loaded into registers up front as
// one fully-coalesced burst of 64 outstanding dword loads; the compiler's
// per-register vmcnt waits let the d-sweep start as soon as plane 0 lands,
// so HBM streaming overlaps the recurrence instead of serializing with it
// (round-0's depth-1 prefetch put a ~900cy HBM wait on every step's
// critical path).
//
// Per step the critical path is only: LDS write + barrier + LDS read at
// (y-1,x-1) (= tid-33, stride-1 across lanes -> conflict-free) + 2 VALU.

#define PLANE 1024              // 32*32
#define DD 32

__global__ __launch_bounds__(1024) void gru3d_preload(
    const float* __restrict__ z,
    const float* __restrict__ ht,
    const float* __restrict__ h0p,
    float* __restrict__ out)
{
    __shared__ float buf[2][PLANE];

    const int bc  = blockIdx.x;           // 0..191
    const int tid = threadIdx.x;          // y*32 + x
    const int y   = tid >> 5;
    const int x   = tid & 31;

    const float* zb = z   + (size_t)bc * (DD * PLANE);
    const float* tb = ht  + (size_t)bc * (DD * PLANE);
    float*       ob = out + (size_t)bc * (DD * PLANE);

    const float h0 = h0p[0];

    // Bulk preload: 64 coalesced dword loads, all in flight at once.
    // Fully unrolled -> static indices -> stays in VGPRs (no scratch).
    float zr[DD], tr[DD];
    #pragma unroll
    for (int d = 0; d < DD; ++d) {
        zr[d] = zb[d * PLANE + tid];
        tr[d] = tb[d * PLANE + tid];
    }

    const bool interior = (y > 0) & (x > 0);

    // d = 0: predecessor is the h0 border everywhere.
    float h = zr[0] * (tr[0] - h0) + h0;   // == z*ht + (1-z)*h0
    ob[tid] = h;
    buf[0][tid] = h;
    __syncthreads();

    #pragma unroll
    for (int d = 1; d < DD; ++d) {
        const float pv = interior ? buf[(d - 1) & 1][tid - 33] : h0;
        const float hn = zr[d] * (tr[d] - pv) + pv;
        ob[d * PLANE + tid] = hn;
        buf[d & 1][tid] = hn;
        __syncthreads();
    }
}

extern "C" void kernel_launch(void* const* d_in, const int* in_sizes, int n_in,
                              void* d_out, int out_size, void* d_ws, size_t ws_size,
                              hipStream_t stream) {
    const float* z  = (const float*)d_in[0];
    const float* ht = (const float*)d_in[1];
    const float* h0 = (const float*)d_in[2];
    float* out      = (float*)d_out;

    const int BC = 2 * 96;                // 192 slabs, one block each
    gru3d_preload<<<dim3(BC), dim3(1024), 0, stream>>>(z, ht, h0, out);
}